// Round 4
// baseline (962.179 us; speedup 1.0000x reference)
//
#include <hip/hip_runtime.h>
#include <hip/hip_fp16.h>
#include <hip/hip_bf16.h>
#include <stdint.h>

// Problem constants
#define LSEQ 524288   // sequence length
// S = I = C = 64, O = 32

// Phase A (PDA state scan): 8192 chunks x 64 steps, 16-step burn-in
#define KA 64
#define WA 16
#define GA (LSEQ / KA)   // 8192 blocks (64 thr each)

// Phase B (counter scan + readout): 1024 chunks x 512 steps, 2560-step burn-in
#define KB 512
#define WB 2560
#define GB (LSEQ / KB)   // 1024 blocks (64 thr each)

// Workspace layout (bytes). Total ~5.27 MB.
#define WS_TP   0u        // uint32[64*64*32]: packed T fp16-pairs, [i][j][s2] = (T[2s2,i,j], T[2s2+1,i,j])
#define WS_IDP  524288u   // uint32[64*64]: (inc_raw[s,i], dec_raw[s,i]) fp16 pair at [i*64+s]
#define WS_WB   540672u   // ushort[32*64]: out_W as bf16, row-major [O][C]
#define WS_INC  544768u   // float[LSEQ]: inc_p
#define WS_DEC  2641920u  // float[LSEQ]: dec_p
#define WS_ST   4739072u  // ushort[64*64*64]: staged softmax(T) fp16, [s][i][j]

typedef __attribute__((ext_vector_type(2))) _Float16 half2v;
typedef __attribute__((ext_vector_type(8))) short short8;
typedef __attribute__((ext_vector_type(4))) float f32x4;
typedef __attribute__((ext_vector_type(4))) uint32_t u32x4;

// ---- DPP controls (gfx9/CDNA encodings)
#define DPP_QUAD_XOR1  0xB1   // quad_perm [1,0,3,2]
#define DPP_ROW_ROR1   0x121
#define DPP_ROW_ROR2   0x122
#define DPP_ROW_ROR4   0x124
#define DPP_ROW_ROR8   0x128
#define DPP_WAVE_SHL1  0x130  // dst[i] = src[i+1], lane63 invalid (bound_ctrl -> 0)
#define DPP_WAVE_ROR1  0x13C  // dst[i] = src[(i-1)&63]
#define DPP_BCAST15    0x142
#define DPP_BCAST31    0x143

template<int CTRL, bool BC>
static __device__ __forceinline__ int dpp_mov_i(int x) {
    return __builtin_amdgcn_update_dpp(0, x, CTRL, 0xF, 0xF, BC);
}
template<int CTRL>
static __device__ __forceinline__ float dpp_mov_f(float x) {
    return __int_as_float(__builtin_amdgcn_update_dpp(0, __float_as_int(x), CTRL, 0xF, 0xF, false));
}
template<int CTRL>
static __device__ __forceinline__ float dpp_mov_f_bc(float x) {
    return __int_as_float(__builtin_amdgcn_update_dpp(0, __float_as_int(x), CTRL, 0xF, 0xF, true));
}

static __device__ __forceinline__ uint32_t h2bits(__half2 h) {
    uint32_t u; __builtin_memcpy(&u, &h, 4); return u;
}
static __device__ __forceinline__ __half2 bits2h(uint32_t u) {
    __half2 h; __builtin_memcpy(&h, &u, 4); return h;
}
static __device__ __forceinline__ uint32_t h2add(uint32_t a, uint32_t b) {
    return h2bits(__hadd2(bits2h(a), bits2h(b)));
}
static __device__ __forceinline__ float rcp_fast(float x) {
#if __has_builtin(__builtin_amdgcn_rcpf)
    return __builtin_amdgcn_rcpf(x);
#else
    return 1.0f / x;
#endif
}
// fp16-pair dot with fp32 accumulate
static __device__ __forceinline__ float dot2acc(uint32_t a, uint32_t b, float c) {
#if __has_builtin(__builtin_amdgcn_fdot2)
    half2v av, bv;
    __builtin_memcpy(&av, &a, 4);
    __builtin_memcpy(&bv, &b, 4);
    return __builtin_amdgcn_fdot2(av, bv, c, false);
#else
    __half2 ah = bits2h(a), bh = bits2h(b);
    float r = c;
    r = fmaf(__half2float(__low2half(ah)),  __half2float(__low2half(bh)),  r);
    r = fmaf(__half2float(__high2half(ah)), __half2float(__high2half(bh)), r);
    return r;
#endif
}
// lane j: pack (state[j&~1], state[j|1]) low/high via quad_perm xor1 (valid in even lanes)
static __device__ __forceinline__ uint32_t pack_state_pair(float st) {
    uint32_t bits = (uint32_t)__half_as_ushort(__float2half(st));
    uint32_t other = (uint32_t)dpp_mov_i<DPP_QUAD_XOR1, false>((int)bits);
    return bits | (other << 16);
}
static __device__ __forceinline__ unsigned short f2bf(float x) {
    __hip_bfloat16 b = __float2bfloat16(x);
    unsigned short u; __builtin_memcpy(&u, &b, 2);
    return u;
}
// full-wave sum of packed fp16 pair: row_ror allreduce + bcast15/31; broadcast from lane 63
static __device__ __forceinline__ uint32_t wave_red_sum_h2(uint32_t v) {
    v = h2add(v, (uint32_t)dpp_mov_i<DPP_ROW_ROR8, false>((int)v));
    v = h2add(v, (uint32_t)dpp_mov_i<DPP_ROW_ROR4, false>((int)v));
    v = h2add(v, (uint32_t)dpp_mov_i<DPP_ROW_ROR2, false>((int)v));
    v = h2add(v, (uint32_t)dpp_mov_i<DPP_ROW_ROR1, false>((int)v));
    v = h2add(v, (uint32_t)dpp_mov_i<DPP_BCAST15, false>((int)v));
    v = h2add(v, (uint32_t)dpp_mov_i<DPP_BCAST31, false>((int)v));
    return (uint32_t)__builtin_amdgcn_readlane((int)v, 63);
}
// 16-lane-group allreduce via row rotations
static __device__ __forceinline__ float grp16_max(float v) {
    v = fmaxf(v, dpp_mov_f<DPP_ROW_ROR8>(v));
    v = fmaxf(v, dpp_mov_f<DPP_ROW_ROR4>(v));
    v = fmaxf(v, dpp_mov_f<DPP_ROW_ROR2>(v));
    v = fmaxf(v, dpp_mov_f<DPP_ROW_ROR1>(v));
    return v;
}
static __device__ __forceinline__ float grp16_sum(float v) {
    v += dpp_mov_f<DPP_ROW_ROR8>(v);
    v += dpp_mov_f<DPP_ROW_ROR4>(v);
    v += dpp_mov_f<DPP_ROW_ROR2>(v);
    v += dpp_mov_f<DPP_ROW_ROR1>(v);
    return v;
}

// ---------------- prep stage 1: softmax rows (coalesced), IDP, W ----------------
__global__ __launch_bounds__(64) void prep_kernel(
    const float* __restrict__ T_raw, const float* __restrict__ inc_raw,
    const float* __restrict__ dec_raw, const float* __restrict__ out_W,
    uint8_t* __restrict__ ws)
{
    int lane = threadIdx.x;
    int bid = blockIdx.x;
    if (bid < 4096) {
        // one wave per (s,i) row: softmax over j, store fp16 coalesced to staged [s][i][j]
        float x = T_raw[bid * 64 + lane];
        float m = x;
        #pragma unroll
        for (int off = 32; off; off >>= 1) m = fmaxf(m, __shfl_xor(m, off));
        float e = __expf(x - m);
        float sum = e;
        #pragma unroll
        for (int off = 32; off; off >>= 1) sum += __shfl_xor(sum, off);
        float v = e / sum;
        ((unsigned short*)(ws + WS_ST))[bid * 64 + lane] = __half_as_ushort(__float2half(v));
    } else if (bid < 4160) {
        int i = bid - 4096;           // lane = s
        float iv = inc_raw[lane * 64 + i];
        float dv = dec_raw[lane * 64 + i];
        __half2 p = __floats2half2_rn(iv, dv);   // low = inc, high = dec
        ((uint32_t*)(ws + WS_IDP))[i * 64 + lane] = h2bits(p);
    } else {
        unsigned short* wbp = (unsigned short*)(ws + WS_WB);
        #pragma unroll
        for (int r = 0; r < 32; ++r) {
            int idx = r * 64 + lane;
            wbp[idx] = f2bf(out_W[idx]);
        }
    }
}

// ---------------- prep stage 2: transpose staged -> packed lane-contiguous TP ----------------
// TP dword (i*64 + j)*32 + s2 = pair (T[2s2,i,j], T[2s2+1,i,j]): lane j's 32 dwords contiguous
__global__ __launch_bounds__(64) void prep2_kernel(uint8_t* __restrict__ ws)
{
    int j = threadIdx.x, i = blockIdx.x;
    const unsigned short* st = (const unsigned short*)(ws + WS_ST);
    uint32_t pk[32];
    #pragma unroll
    for (int s2 = 0; s2 < 32; ++s2) {
        uint32_t lo = st[(2 * s2) * 4096 + i * 64 + j];
        uint32_t hi = st[(2 * s2 + 1) * 4096 + i * 64 + j];
        pk[s2] = lo | (hi << 16);
    }
    u32x4* dst = (u32x4*)(ws + WS_TP) + (size_t)(i * 64 + j) * 8;
    #pragma unroll
    for (int q = 0; q < 8; ++q) {
        u32x4 v = { pk[4 * q], pk[4 * q + 1], pk[4 * q + 2], pk[4 * q + 3] };
        dst[q] = v;
    }
}

// ---------------- phase A: PDA state scan ----------------
// T tile loads: 8 global_load_dwordx4 per step (lane-contiguous packed layout),
// wave-uniform row base (readfirstlane'd symbol).
static __device__ __forceinline__ void pda_step(
    int k, int warm, int t0, int tstart, int lane,
    const int* __restrict__ seq,
    const u32x4* __restrict__ Tp, const uint32_t* __restrict__ IDP,
    u32x4 (&Tcur)[8], u32x4 (&Tnxt)[8],
    uint32_t& idc, int& inpA,
    float& st, uint32_t& pk,
    float& incK, float& decK,
    float* __restrict__ incArr, float* __restrict__ decArr)
{
    // scalar prefetch of input 2 steps ahead; T/incdec prefetch 1 step ahead
    int nidx = tstart + k + 2;
    nidx = nidx < (LSEQ - 1) ? nidx : (LSEQ - 1);
    int inpB = (int)__builtin_amdgcn_readfirstlane(seq[nidx]);
    {
        const u32x4* Trow = Tp + (size_t)inpA * 512 + lane * 8;  // uniform base + lane*128B
        #pragma unroll
        for (int q = 0; q < 8; ++q)
            Tnxt[q] = Trow[q];
    }
    uint32_t idn = (IDP + inpA * 64)[lane];

    // inc/dec logits from current (pre-update) state: packed-fp16 DPP allreduce
    __half2 idh = bits2h(idc);
    float ih = __half2float(__low2half(idh));
    float dh = __half2float(__high2half(idh));
    uint32_t prb = h2bits(__floats2half2_rn(st * ih, st * dh));
    uint32_t tot = wave_red_sum_h2(prb);
    float inc_l = __half2float(__ushort_as_half((unsigned short)(tot & 0xFFFFu)));
    float dec_l = __half2float(__ushort_as_half((unsigned short)(tot >> 16)));
    // softmax over {inc_l, dec_l, 0}: logits tiny, skip max-shift
    float e0 = __expf(inc_l);
    float e1 = __expf(dec_l);
    float rs = rcp_fast(e0 + e1 + 1.0f);
    float pi = e0 * rs, pd = e1 * rs;

    // state matvec: lane j owns new_state[j] = sum_s state[s]*T[s,inp,j]
    float a0 = 0.f, a1 = 0.f, a2 = 0.f, a3 = 0.f;
    #pragma unroll
    for (int s2 = 0; s2 < 8; ++s2) {
        a0 = dot2acc(Tcur[s2 >> 2][s2 & 3],
                     (uint32_t)__builtin_amdgcn_readlane(pk, 2 * s2), a0);
        a1 = dot2acc(Tcur[(s2 + 8) >> 2][s2 & 3],
                     (uint32_t)__builtin_amdgcn_readlane(pk, 2 * (s2 + 8)), a1);
        a2 = dot2acc(Tcur[(s2 + 16) >> 2][s2 & 3],
                     (uint32_t)__builtin_amdgcn_readlane(pk, 2 * (s2 + 16)), a2);
        a3 = dot2acc(Tcur[(s2 + 24) >> 2][s2 & 3],
                     (uint32_t)__builtin_amdgcn_readlane(pk, 2 * (s2 + 24)), a3);
    }
    float ns = (a0 + a1) + (a2 + a3);

    // emit probs (keep step k's value in lane (k mod 64); coalesced flush every 64 steps)
    if (k >= warm) {
        int loc = k - warm;
        int sl = loc & 63;
        if (lane == sl) { incK = pi; decK = pd; }
        if (sl == 63) {
            int base = t0 + loc - 63;
            incArr[base + lane] = incK;
            decArr[base + lane] = decK;
        }
    }

    st = ns;
    pk = pack_state_pair(st);
    idc = idn;
    inpA = inpB;
}

__global__ __launch_bounds__(64, 4) void pda_kernel(
    const int* __restrict__ seq, const float* __restrict__ initv,
    uint8_t* __restrict__ ws)
{
    int lane = threadIdx.x;
    int g = blockIdx.x;
    const u32x4* Tp = (const u32x4*)(ws + WS_TP);
    const uint32_t* IDP = (const uint32_t*)(ws + WS_IDP);
    float* incArr = (float*)(ws + WS_INC);
    float* decArr = (float*)(ws + WS_DEC);

    int t0 = g * KA;
    int warm = (g == 0) ? 0 : WA;     // chunk 0 starts from the true initial state
    int tstart = t0 - warm;
    int nsteps = KA + warm;           // 64 or 80 (both even)

    float st;
    if (g == 0) {
        float x = initv[lane];        // state0 = softmax(init)
        float m = x;
        #pragma unroll
        for (int off = 32; off; off >>= 1) m = fmaxf(m, __shfl_xor(m, off));
        float e = __expf(x - m);
        float s = e;
        #pragma unroll
        for (int off = 32; off; off >>= 1) s += __shfl_xor(s, off);
        st = e / s;
    } else {
        st = 1.0f / 64.0f;            // burn-in init; forgotten within ~10 steps (Dobrushin ~0.1)
    }
    uint32_t pk = pack_state_pair(st);

    int inp0 = (int)__builtin_amdgcn_readfirstlane(seq[tstart]);
    int i1 = tstart + 1; i1 = i1 < (LSEQ - 1) ? i1 : (LSEQ - 1);
    int inpA = (int)__builtin_amdgcn_readfirstlane(seq[i1]);

    u32x4 Tc[8], Tn[8];
    {
        const u32x4* Trow = Tp + (size_t)inp0 * 512 + lane * 8;
        #pragma unroll
        for (int q = 0; q < 8; ++q)
            Tc[q] = Trow[q];
    }
    uint32_t idc = (IDP + inp0 * 64)[lane];

    float incK = 0.f, decK = 0.f;

    for (int k = 0; k < nsteps; k += 2) {   // ping-pong T buffers
        pda_step(k,     warm, t0, tstart, lane, seq, Tp, IDP, Tc, Tn,
                 idc, inpA, st, pk, incK, decK, incArr, decArr);
        pda_step(k + 1, warm, t0, tstart, lane, seq, Tp, IDP, Tn, Tc,
                 idc, inpA, st, pk, incK, decK, incArr, decArr);
    }
}

// ---------------- phase B: counter scan + batched MFMA readout ----------------
// Recurrence: dist' = fma(dec, fma(-m1,dist,dn), fma(inc, up-dist, dist))
//   up = wave_ror1(dist), dn = wave_shl1(dist) [bound_ctrl->0], m1 = (lane!=0)
//   (clip dropped: softmax guarantees inc+dec < 1). Scalars inc/dec come from
//   wave-uniform loads (s_load clusters), fully off the dependency chain.
__global__ __launch_bounds__(64) void counter_kernel(
    const float* __restrict__ out_b, float* __restrict__ out,
    uint8_t* __restrict__ ws)
{
    __shared__ unsigned short stage[64 * 72];   // 64 staged dist rows, stride 72 halves
    int lane = threadIdx.x;
    int g = blockIdx.x;
    const float* __restrict__ incArr = (const float*)(ws + WS_INC);
    const float* __restrict__ decArr = (const float*)(ws + WS_DEC);
    const unsigned short* wbp = (const unsigned short*)(ws + WS_WB);

    int t0 = g * KB;
    bool exact = (t0 <= WB);          // early chunks replay exactly from t=0 (one-hot init)
    int warm = exact ? t0 : WB;       // multiple of 64
    int tstart = t0 - warm;

    float dist = exact ? (lane == 0 ? 1.0f : 0.0f) : (1.0f / 64.0f);
    float m1n = (lane == 0) ? 0.0f : -1.0f;   // -(lane!=0), constant

    int q = lane >> 4, c16 = lane & 15;
    // B-operand frags: lane holds W[n = nt*16 + c16][k = kb*32 + q*8 + j]
    short8 wf00, wf01, wf10, wf11;
    {
        int n0 = c16, n1 = 16 + c16;
        int kk = q * 8;
        wf00 = *(const short8*)(wbp + n0 * 64 + kk);
        wf10 = *(const short8*)(wbp + n0 * 64 + 32 + kk);
        wf01 = *(const short8*)(wbp + n1 * 64 + kk);
        wf11 = *(const short8*)(wbp + n1 * 64 + 32 + kk);
    }
    float b0 = out_b[c16], b1 = out_b[16 + c16];

    // ---- warm batches: recurrence only, 32-step unrolled, scalar prob loads ----
    int wq = warm >> 5;
    for (int b = 0; b < wq; ++b) {
        int base = tstart + b * 32;
        #pragma unroll
        for (int j = 0; j < 32; ++j) {
            float inc = incArr[base + j];   // wave-uniform -> scalar load
            float dec = decArr[base + j];
            float up = dpp_mov_f<DPP_WAVE_ROR1>(dist);
            float dn = dpp_mov_f_bc<DPP_WAVE_SHL1>(dist);
            float t2 = fmaf(m1n, dist, dn);
            dist = fmaf(dec, t2, fmaf(inc, up - dist, dist));
        }
    }

    // ---- emit batches: stage 64 rows (2x32 steps), then 4 MFMA epilogues ----
    for (int eb = 0; eb < (KB >> 6); ++eb) {
        #pragma unroll
        for (int h = 0; h < 2; ++h) {
            int base = t0 + eb * 64 + h * 32;
            #pragma unroll
            for (int j = 0; j < 32; ++j) {
                stage[(h * 32 + j) * 72 + lane] = f2bf(dist);   // PRE-update dist row
                float inc = incArr[base + j];
                float dec = decArr[base + j];
                float up = dpp_mov_f<DPP_WAVE_ROR1>(dist);
                float dn = dpp_mov_f_bc<DPP_WAVE_SHL1>(dist);
                float t2 = fmaf(m1n, dist, dn);
                dist = fmaf(dec, t2, fmaf(inc, up - dist, dist));
            }
        }
        int rowbase0 = t0 + eb * 64;
        #pragma unroll
        for (int t = 0; t < 4; ++t) {
            // same-wave LDS ordering: staging writes complete before these reads
            const unsigned short* sp = stage + (t * 16 + c16) * 72;
            short8 a0 = *(const short8*)(sp + q * 8);        // k 0..31
            short8 a1 = *(const short8*)(sp + 32 + q * 8);   // k 32..63
            f32x4 d0 = {0.f, 0.f, 0.f, 0.f};
            f32x4 d1 = {0.f, 0.f, 0.f, 0.f};
            d0 = __builtin_amdgcn_mfma_f32_16x16x32_bf16(a0, wf00, d0, 0, 0, 0);
            d0 = __builtin_amdgcn_mfma_f32_16x16x32_bf16(a1, wf10, d0, 0, 0, 0);
            d1 = __builtin_amdgcn_mfma_f32_16x16x32_bf16(a0, wf01, d1, 0, 0, 0);
            d1 = __builtin_amdgcn_mfma_f32_16x16x32_bf16(a1, wf11, d1, 0, 0, 0);
            int rowbase = rowbase0 + t * 16;
            // C/D: col = lane&15, row = q*4 + r -> softmax over 32 outputs per row
            #pragma unroll
            for (int r = 0; r < 4; ++r) {
                float l0 = d0[r] + b0, l1 = d1[r] + b1;
                float mm = grp16_max(fmaxf(l0, l1));
                float e0 = __expf(l0 - mm), e1 = __expf(l1 - mm);
                float ssum = grp16_sum(e0 + e1);
                float rinv = rcp_fast(ssum);
                int row = rowbase + q * 4 + r;
                out[row * 32 + c16]      = e0 * rinv;
                out[row * 32 + 16 + c16] = e1 * rinv;
            }
        }
    }
}

extern "C" void kernel_launch(void* const* d_in, const int* in_sizes, int n_in,
                              void* d_out, int out_size, void* d_ws, size_t ws_size,
                              hipStream_t stream) {
    const int*   seq     = (const int*)d_in[0];
    const float* T_raw   = (const float*)d_in[1];
    const float* inc_raw = (const float*)d_in[2];
    const float* dec_raw = (const float*)d_in[3];
    const float* out_W   = (const float*)d_in[4];
    const float* out_b   = (const float*)d_in[5];
    const float* initv   = (const float*)d_in[6];
    float* out = (float*)d_out;
    uint8_t* ws = (uint8_t*)d_ws;
    (void)in_sizes; (void)n_in; (void)out_size; (void)ws_size;

    hipLaunchKernelGGL(prep_kernel, dim3(4161), dim3(64), 0, stream,
                       T_raw, inc_raw, dec_raw, out_W, ws);
    hipLaunchKernelGGL(prep2_kernel, dim3(64), dim3(64), 0, stream, ws);
    hipLaunchKernelGGL(pda_kernel, dim3(GA), dim3(64), 0, stream, seq, initv, ws);
    hipLaunchKernelGGL(counter_kernel, dim3(GB), dim3(64), 0, stream, out_b, out, ws);
}

// Round 5
// 318.736 us; speedup vs baseline: 3.0187x; 3.0187x over previous
//
#include <hip/hip_runtime.h>
#include <hip/hip_fp16.h>
#include <hip/hip_bf16.h>
#include <stdint.h>

// Problem constants
#define LSEQ 524288   // sequence length
// S = I = C = 64, O = 32

// Phase A (PDA state scan): 4096 chunks x 128 steps, 16-step burn-in
#define KA 128
#define WA 16
#define GA (LSEQ / KA)   // 4096 blocks (64 thr each)

// Phase B (counter scan + readout): 2048 chunks x 256 steps, 2560-step burn-in
#define KB 256
#define WB 2560
#define GB (LSEQ / KB)   // 2048 blocks (64 thr each)

// Workspace layout (bytes). Total ~5.27 MB.
#define WS_TP   0u        // uint32[64*2048]: packed T fp16-pairs; tile i, dword (q*64+j)*4+r = (T[2(4q+r),i,j], T[2(4q+r)+1,i,j])
#define WS_IDP  524288u   // uint32[64*64]: (inc_raw[s,i], dec_raw[s,i]) fp16 pair at [i*64+s]
#define WS_WB   540672u   // ushort[32*64]: out_W as bf16, row-major [O][C]
#define WS_INC  544768u   // float[LSEQ]: inc_p
#define WS_DEC  2641920u  // float[LSEQ]: dec_p
#define WS_ST   4739072u  // ushort[64*64*64]: staged softmax(T) fp16, [s][i][j]

typedef __attribute__((ext_vector_type(2))) _Float16 half2v;
typedef __attribute__((ext_vector_type(8))) short short8;
typedef __attribute__((ext_vector_type(4))) float f32x4;
typedef __attribute__((ext_vector_type(4))) uint32_t u32x4;

// ---- DPP controls (gfx9/CDNA encodings)
#define DPP_QUAD_XOR1  0xB1   // quad_perm [1,0,3,2]
#define DPP_ROW_ROR1   0x121
#define DPP_ROW_ROR2   0x122
#define DPP_ROW_ROR4   0x124
#define DPP_ROW_ROR8   0x128
#define DPP_WAVE_SHL1  0x130  // dst[i] = src[i+1], lane63 invalid (bound_ctrl -> 0)
#define DPP_WAVE_ROR1  0x13C  // dst[i] = src[(i-1)&63]
#define DPP_BCAST15    0x142
#define DPP_BCAST31    0x143

template<int CTRL, bool BC>
static __device__ __forceinline__ int dpp_mov_i(int x) {
    return __builtin_amdgcn_update_dpp(0, x, CTRL, 0xF, 0xF, BC);
}
template<int CTRL>
static __device__ __forceinline__ float dpp_mov_f(float x) {
    return __int_as_float(__builtin_amdgcn_update_dpp(0, __float_as_int(x), CTRL, 0xF, 0xF, false));
}
template<int CTRL>
static __device__ __forceinline__ float dpp_mov_f_bc(float x) {
    return __int_as_float(__builtin_amdgcn_update_dpp(0, __float_as_int(x), CTRL, 0xF, 0xF, true));
}

static __device__ __forceinline__ uint32_t h2bits(__half2 h) {
    uint32_t u; __builtin_memcpy(&u, &h, 4); return u;
}
static __device__ __forceinline__ __half2 bits2h(uint32_t u) {
    __half2 h; __builtin_memcpy(&h, &u, 4); return h;
}
static __device__ __forceinline__ uint32_t h2add(uint32_t a, uint32_t b) {
    return h2bits(__hadd2(bits2h(a), bits2h(b)));
}
static __device__ __forceinline__ float rcp_fast(float x) {
#if __has_builtin(__builtin_amdgcn_rcpf)
    return __builtin_amdgcn_rcpf(x);
#else
    return 1.0f / x;
#endif
}
// fp16-pair dot with fp32 accumulate
static __device__ __forceinline__ float dot2acc(uint32_t a, uint32_t b, float c) {
#if __has_builtin(__builtin_amdgcn_fdot2)
    half2v av, bv;
    __builtin_memcpy(&av, &a, 4);
    __builtin_memcpy(&bv, &b, 4);
    return __builtin_amdgcn_fdot2(av, bv, c, false);
#else
    __half2 ah = bits2h(a), bh = bits2h(b);
    float r = c;
    r = fmaf(__half2float(__low2half(ah)),  __half2float(__low2half(bh)),  r);
    r = fmaf(__half2float(__high2half(ah)), __half2float(__high2half(bh)), r);
    return r;
#endif
}
// lane j: pack (state[j&~1], state[j|1]) low/high via quad_perm xor1 (valid in even lanes)
static __device__ __forceinline__ uint32_t pack_state_pair(float st) {
    uint32_t bits = (uint32_t)__half_as_ushort(__float2half(st));
    uint32_t other = (uint32_t)dpp_mov_i<DPP_QUAD_XOR1, false>((int)bits);
    return bits | (other << 16);
}
static __device__ __forceinline__ unsigned short f2bf(float x) {
    __hip_bfloat16 b = __float2bfloat16(x);
    unsigned short u; __builtin_memcpy(&u, &b, 2);
    return u;
}
static __device__ __forceinline__ float bcast_lane_f(float v, int lane) {
    return __int_as_float(__builtin_amdgcn_readlane(__float_as_int(v), lane));
}
// full-wave sum of packed fp16 pair: row_ror allreduce + bcast15/31; broadcast from lane 63
static __device__ __forceinline__ uint32_t wave_red_sum_h2(uint32_t v) {
    v = h2add(v, (uint32_t)dpp_mov_i<DPP_ROW_ROR8, false>((int)v));
    v = h2add(v, (uint32_t)dpp_mov_i<DPP_ROW_ROR4, false>((int)v));
    v = h2add(v, (uint32_t)dpp_mov_i<DPP_ROW_ROR2, false>((int)v));
    v = h2add(v, (uint32_t)dpp_mov_i<DPP_ROW_ROR1, false>((int)v));
    v = h2add(v, (uint32_t)dpp_mov_i<DPP_BCAST15, false>((int)v));
    v = h2add(v, (uint32_t)dpp_mov_i<DPP_BCAST31, false>((int)v));
    return (uint32_t)__builtin_amdgcn_readlane((int)v, 63);
}
// 16-lane-group allreduce via row rotations
static __device__ __forceinline__ float grp16_max(float v) {
    v = fmaxf(v, dpp_mov_f<DPP_ROW_ROR8>(v));
    v = fmaxf(v, dpp_mov_f<DPP_ROW_ROR4>(v));
    v = fmaxf(v, dpp_mov_f<DPP_ROW_ROR2>(v));
    v = fmaxf(v, dpp_mov_f<DPP_ROW_ROR1>(v));
    return v;
}
static __device__ __forceinline__ float grp16_sum(float v) {
    v += dpp_mov_f<DPP_ROW_ROR8>(v);
    v += dpp_mov_f<DPP_ROW_ROR4>(v);
    v += dpp_mov_f<DPP_ROW_ROR2>(v);
    v += dpp_mov_f<DPP_ROW_ROR1>(v);
    return v;
}

// ---------------- prep stage 1: softmax rows (coalesced), IDP, W ----------------
__global__ __launch_bounds__(64) void prep_kernel(
    const float* __restrict__ T_raw, const float* __restrict__ inc_raw,
    const float* __restrict__ dec_raw, const float* __restrict__ out_W,
    uint8_t* __restrict__ ws)
{
    int lane = threadIdx.x;
    int bid = blockIdx.x;
    if (bid < 4096) {
        // one wave per (s,i) row: softmax over j, store fp16 coalesced to staged [s][i][j]
        float x = T_raw[bid * 64 + lane];
        float m = x;
        #pragma unroll
        for (int off = 32; off; off >>= 1) m = fmaxf(m, __shfl_xor(m, off));
        float e = __expf(x - m);
        float sum = e;
        #pragma unroll
        for (int off = 32; off; off >>= 1) sum += __shfl_xor(sum, off);
        float v = e / sum;
        ((unsigned short*)(ws + WS_ST))[bid * 64 + lane] = __half_as_ushort(__float2half(v));
    } else if (bid < 4160) {
        int i = bid - 4096;           // lane = s
        float iv = inc_raw[lane * 64 + i];
        float dv = dec_raw[lane * 64 + i];
        __half2 p = __floats2half2_rn(iv, dv);   // low = inc, high = dec
        ((uint32_t*)(ws + WS_IDP))[i * 64 + lane] = h2bits(p);
    } else {
        unsigned short* wbp = (unsigned short*)(ws + WS_WB);
        #pragma unroll
        for (int r = 0; r < 32; ++r) {
            int idx = r * 64 + lane;
            wbp[idx] = f2bf(out_W[idx]);
        }
    }
}

// ---------------- prep stage 2: transpose staged -> packed coalesced TP ----------------
// Tile i (2048 dwords): dword (q*64 + j)*4 + r = pair (T[2(4q+r),i,j], T[2(4q+r)+1,i,j]).
// pda then loads u32x4 at index q*64 + j: lanes j consecutive -> fully coalesced 1KB/instr,
// and lane j's vector q component r is pair s2 = 4q + r (same indexing as the dot loop).
__global__ __launch_bounds__(64) void prep2_kernel(uint8_t* __restrict__ ws)
{
    int j = threadIdx.x, i = blockIdx.x;
    const unsigned short* st = (const unsigned short*)(ws + WS_ST);
    uint32_t pk[32];
    #pragma unroll
    for (int s2 = 0; s2 < 32; ++s2) {
        uint32_t lo = st[(2 * s2) * 4096 + i * 64 + j];
        uint32_t hi = st[(2 * s2 + 1) * 4096 + i * 64 + j];
        pk[s2] = lo | (hi << 16);
    }
    u32x4* dst = (u32x4*)(ws + WS_TP) + (size_t)i * 512;
    #pragma unroll
    for (int q = 0; q < 8; ++q) {
        u32x4 v = { pk[4 * q], pk[4 * q + 1], pk[4 * q + 2], pk[4 * q + 3] };
        dst[q * 64 + j] = v;   // lanes consecutive -> coalesced store
    }
}

// ---------------- phase A: PDA state scan ----------------
// T tile: 8 coalesced global_load_dwordx4 per step, wave-uniform row base.
static __device__ __forceinline__ void pda_step(
    int k, int warm, int t0, int tstart, int lane,
    const int* __restrict__ seq,
    const u32x4* __restrict__ Tp, const uint32_t* __restrict__ IDP,
    u32x4 (&Tcur)[8], u32x4 (&Tnxt)[8],
    uint32_t& idc, int& inpA,
    float& st, uint32_t& pk,
    float& incK, float& decK,
    float* __restrict__ incArr, float* __restrict__ decArr)
{
    // scalar prefetch of input 2 steps ahead; T/incdec prefetch 1 step ahead
    int nidx = tstart + k + 2;
    nidx = nidx < (LSEQ - 1) ? nidx : (LSEQ - 1);
    int inpB = (int)__builtin_amdgcn_readfirstlane(seq[nidx]);
    {
        const u32x4* Trow = Tp + (size_t)inpA * 512 + lane;  // uniform base + lane*16B
        #pragma unroll
        for (int q = 0; q < 8; ++q)
            Tnxt[q] = Trow[q * 64];
    }
    uint32_t idn = (IDP + inpA * 64)[lane];

    // inc/dec logits from current (pre-update) state: packed-fp16 DPP allreduce
    __half2 idh = bits2h(idc);
    float ih = __half2float(__low2half(idh));
    float dh = __half2float(__high2half(idh));
    uint32_t prb = h2bits(__floats2half2_rn(st * ih, st * dh));
    uint32_t tot = wave_red_sum_h2(prb);
    float inc_l = __half2float(__ushort_as_half((unsigned short)(tot & 0xFFFFu)));
    float dec_l = __half2float(__ushort_as_half((unsigned short)(tot >> 16)));
    // softmax over {inc_l, dec_l, 0}: logits tiny, skip max-shift
    float e0 = __expf(inc_l);
    float e1 = __expf(dec_l);
    float rs = rcp_fast(e0 + e1 + 1.0f);
    float pi = e0 * rs, pd = e1 * rs;

    // state matvec: lane j owns new_state[j] = sum_s state[s]*T[s,inp,j]
    float a0 = 0.f, a1 = 0.f, a2 = 0.f, a3 = 0.f;
    #pragma unroll
    for (int s2 = 0; s2 < 8; ++s2) {
        a0 = dot2acc(Tcur[s2 >> 2][s2 & 3],
                     (uint32_t)__builtin_amdgcn_readlane(pk, 2 * s2), a0);
        a1 = dot2acc(Tcur[(s2 + 8) >> 2][s2 & 3],
                     (uint32_t)__builtin_amdgcn_readlane(pk, 2 * (s2 + 8)), a1);
        a2 = dot2acc(Tcur[(s2 + 16) >> 2][s2 & 3],
                     (uint32_t)__builtin_amdgcn_readlane(pk, 2 * (s2 + 16)), a2);
        a3 = dot2acc(Tcur[(s2 + 24) >> 2][s2 & 3],
                     (uint32_t)__builtin_amdgcn_readlane(pk, 2 * (s2 + 24)), a3);
    }
    float ns = (a0 + a1) + (a2 + a3);

    // emit probs (keep step k's value in lane (k mod 64); coalesced flush every 64 steps)
    if (k >= warm) {
        int loc = k - warm;
        int sl = loc & 63;
        if (lane == sl) { incK = pi; decK = pd; }
        if (sl == 63) {
            int base = t0 + loc - 63;
            incArr[base + lane] = incK;
            decArr[base + lane] = decK;
        }
    }

    st = ns;
    pk = pack_state_pair(st);
    idc = idn;
    inpA = inpB;
}

__global__ __launch_bounds__(64, 4) void pda_kernel(
    const int* __restrict__ seq, const float* __restrict__ initv,
    uint8_t* __restrict__ ws)
{
    int lane = threadIdx.x;
    int g = blockIdx.x;
    const u32x4* Tp = (const u32x4*)(ws + WS_TP);
    const uint32_t* IDP = (const uint32_t*)(ws + WS_IDP);
    float* incArr = (float*)(ws + WS_INC);
    float* decArr = (float*)(ws + WS_DEC);

    int t0 = g * KA;
    int warm = (g == 0) ? 0 : WA;     // chunk 0 starts from the true initial state
    int tstart = t0 - warm;
    int nsteps = KA + warm;           // 128 or 144 (both even)

    float st;
    if (g == 0) {
        float x = initv[lane];        // state0 = softmax(init)
        float m = x;
        #pragma unroll
        for (int off = 32; off; off >>= 1) m = fmaxf(m, __shfl_xor(m, off));
        float e = __expf(x - m);
        float s = e;
        #pragma unroll
        for (int off = 32; off; off >>= 1) s += __shfl_xor(s, off);
        st = e / s;
    } else {
        st = 1.0f / 64.0f;            // burn-in init; forgotten within ~10 steps (Dobrushin ~0.1)
    }
    uint32_t pk = pack_state_pair(st);

    int inp0 = (int)__builtin_amdgcn_readfirstlane(seq[tstart]);
    int i1 = tstart + 1; i1 = i1 < (LSEQ - 1) ? i1 : (LSEQ - 1);
    int inpA = (int)__builtin_amdgcn_readfirstlane(seq[i1]);

    u32x4 Tc[8], Tn[8];
    {
        const u32x4* Trow = Tp + (size_t)inp0 * 512 + lane;
        #pragma unroll
        for (int q = 0; q < 8; ++q)
            Tc[q] = Trow[q * 64];
    }
    uint32_t idc = (IDP + inp0 * 64)[lane];

    float incK = 0.f, decK = 0.f;

    for (int k = 0; k < nsteps; k += 2) {   // ping-pong T buffers
        pda_step(k,     warm, t0, tstart, lane, seq, Tp, IDP, Tc, Tn,
                 idc, inpA, st, pk, incK, decK, incArr, decArr);
        pda_step(k + 1, warm, t0, tstart, lane, seq, Tp, IDP, Tn, Tc,
                 idc, inpA, st, pk, incK, decK, incArr, decArr);
    }
}

// ---------------- phase B: counter scan + batched MFMA readout ----------------
// 64-step batches: vector-load 64 probs (coalesced), broadcast via literal-index
// v_readlane (off the dist chain). Chain: dist' = fma(dec, fma(m1n,dist,dn),
// fma(inc, up-dist, dist)); up = wave_ror1, dn = wave_shl1 (bound_ctrl->0),
// m1n = -(lane!=0). Clip dropped (softmax guarantees inc+dec < 1).
__global__ __launch_bounds__(64) void counter_kernel(
    const float* __restrict__ out_b, float* __restrict__ out,
    uint8_t* __restrict__ ws)
{
    __shared__ unsigned short stage[64 * 72];   // 64 staged dist rows, stride 72 halves
    int lane = threadIdx.x;
    int g = blockIdx.x;
    const float* __restrict__ incArr = (const float*)(ws + WS_INC);
    const float* __restrict__ decArr = (const float*)(ws + WS_DEC);
    const unsigned short* wbp = (const unsigned short*)(ws + WS_WB);

    int t0 = g * KB;
    bool exact = (t0 <= WB);          // early chunks replay exactly from t=0 (one-hot init)
    int warm = exact ? t0 : WB;       // multiple of 64
    int tstart = t0 - warm;
    int nb  = (warm + KB) >> 6;       // total 64-step batches
    int nwb = warm >> 6;              // warm batches

    float dist = exact ? (lane == 0 ? 1.0f : 0.0f) : (1.0f / 64.0f);
    float m1n = (lane == 0) ? 0.0f : -1.0f;   // -(lane!=0), constant

    int q = lane >> 4, c16 = lane & 15;
    // B-operand frags: lane holds W[n = nt*16 + c16][k = kb*32 + q*8 + j]
    short8 wf00, wf01, wf10, wf11;
    {
        int n0 = c16, n1 = 16 + c16;
        int kk = q * 8;
        wf00 = *(const short8*)(wbp + n0 * 64 + kk);
        wf10 = *(const short8*)(wbp + n0 * 64 + 32 + kk);
        wf01 = *(const short8*)(wbp + n1 * 64 + kk);
        wf11 = *(const short8*)(wbp + n1 * 64 + 32 + kk);
    }
    float b0 = out_b[c16], b1 = out_b[16 + c16];

    // batch 0 inc/dec loads (coalesced, 64 steps per load)
    float ivA = incArr[tstart + lane];
    float dvA = decArr[tstart + lane];
    float ivB = 0.f, dvB = 0.f;

    // ---- warm batches: recurrence only, double-buffered prob loads ----
    for (int b = 0; b < nwb; ++b) {
        int nidx = tstart + (b + 1) * 64 + lane;   // b+1 <= nwb => in range
        ivB = incArr[nidx];
        dvB = decArr[nidx];
        #pragma unroll
        for (int j = 0; j < 64; ++j) {
            float inc = bcast_lane_f(ivA, j);
            float dec = bcast_lane_f(dvA, j);
            float up = dpp_mov_f<DPP_WAVE_ROR1>(dist);
            float dn = dpp_mov_f_bc<DPP_WAVE_SHL1>(dist);
            float t2 = fmaf(m1n, dist, dn);
            dist = fmaf(dec, t2, fmaf(inc, up - dist, dist));
        }
        ivA = ivB; dvA = dvB;
    }

    // ---- emit batches: stage 64 rows, then 4 MFMA epilogues ----
    int neb = nb - nwb;   // = KB/64 = 4
    for (int eb = 0; eb < neb; ++eb) {
        int b = nwb + eb;
        if (b + 1 < nb) {
            int nidx = tstart + (b + 1) * 64 + lane;
            ivB = incArr[nidx];
            dvB = decArr[nidx];
        }
        #pragma unroll
        for (int j = 0; j < 64; ++j) {
            stage[j * 72 + lane] = f2bf(dist);      // PRE-update dist row
            float inc = bcast_lane_f(ivA, j);
            float dec = bcast_lane_f(dvA, j);
            float up = dpp_mov_f<DPP_WAVE_ROR1>(dist);
            float dn = dpp_mov_f_bc<DPP_WAVE_SHL1>(dist);
            float t2 = fmaf(m1n, dist, dn);
            dist = fmaf(dec, t2, fmaf(inc, up - dist, dist));
        }
        int rowbase0 = t0 + eb * 64;
        #pragma unroll
        for (int t = 0; t < 4; ++t) {
            // same-wave LDS ordering: staging writes complete before these reads
            const unsigned short* sp = stage + (t * 16 + c16) * 72;
            short8 a0 = *(const short8*)(sp + q * 8);        // k 0..31
            short8 a1 = *(const short8*)(sp + 32 + q * 8);   // k 32..63
            f32x4 d0 = {0.f, 0.f, 0.f, 0.f};
            f32x4 d1 = {0.f, 0.f, 0.f, 0.f};
            d0 = __builtin_amdgcn_mfma_f32_16x16x32_bf16(a0, wf00, d0, 0, 0, 0);
            d0 = __builtin_amdgcn_mfma_f32_16x16x32_bf16(a1, wf10, d0, 0, 0, 0);
            d1 = __builtin_amdgcn_mfma_f32_16x16x32_bf16(a0, wf01, d1, 0, 0, 0);
            d1 = __builtin_amdgcn_mfma_f32_16x16x32_bf16(a1, wf11, d1, 0, 0, 0);
            int rowbase = rowbase0 + t * 16;
            // C/D: col = lane&15, row = q*4 + r -> softmax over 32 outputs per row
            #pragma unroll
            for (int r = 0; r < 4; ++r) {
                float l0 = d0[r] + b0, l1 = d1[r] + b1;
                float mm = grp16_max(fmaxf(l0, l1));
                float e0 = __expf(l0 - mm), e1 = __expf(l1 - mm);
                float ssum = grp16_sum(e0 + e1);
                float rinv = rcp_fast(ssum);
                int row = rowbase + q * 4 + r;
                out[row * 32 + c16]      = e0 * rinv;
                out[row * 32 + 16 + c16] = e1 * rinv;
            }
        }
        ivA = ivB; dvA = dvB;
    }
}

extern "C" void kernel_launch(void* const* d_in, const int* in_sizes, int n_in,
                              void* d_out, int out_size, void* d_ws, size_t ws_size,
                              hipStream_t stream) {
    const int*   seq     = (const int*)d_in[0];
    const float* T_raw   = (const float*)d_in[1];
    const float* inc_raw = (const float*)d_in[2];
    const float* dec_raw = (const float*)d_in[3];
    const float* out_W   = (const float*)d_in[4];
    const float* out_b   = (const float*)d_in[5];
    const float* initv   = (const float*)d_in[6];
    float* out = (float*)d_out;
    uint8_t* ws = (uint8_t*)d_ws;
    (void)in_sizes; (void)n_in; (void)out_size; (void)ws_size;

    hipLaunchKernelGGL(prep_kernel, dim3(4161), dim3(64), 0, stream,
                       T_raw, inc_raw, dec_raw, out_W, ws);
    hipLaunchKernelGGL(prep2_kernel, dim3(64), dim3(64), 0, stream, ws);
    hipLaunchKernelGGL(pda_kernel, dim3(GA), dim3(64), 0, stream, seq, initv, ws);
    hipLaunchKernelGGL(counter_kernel, dim3(GB), dim3(64), 0, stream, out_b, out, ws);
}